// Round 1
// baseline (456.621 us; speedup 1.0000x reference)
//
#include <hip/hip_runtime.h>

typedef __attribute__((ext_vector_type(4))) float f32x4;

#define NTHREADS 256
#define S 10
#define D 100
#define H 16
#define NITER 5

__global__ __launch_bounds__(NTHREADS, 1)
void attn_greedy_kernel(const float* __restrict__ user_intent,
                        const float* __restrict__ item_corpus,
                        const float* __restrict__ W_proj,
                        const float* __restrict__ b_proj,
                        const float* __restrict__ W_k,
                        const float* __restrict__ b_k,
                        float* __restrict__ out)
{
    // Weights staged once per block; all later reads are wave-uniform
    // broadcast addresses -> conflict-free LDS reads.
    __shared__ f32x4 s_wp[D * H / 4];  // (100,16) row-major, quad over h
    __shared__ f32x4 s_wk[H * H / 4];  // (16,16)  row-major, quad over h
    __shared__ f32x4 s_bp[H / 4];
    __shared__ f32x4 s_bk[H / 4];

    {
        float* p = (float*)s_wp;
        for (int i = threadIdx.x; i < D * H; i += NTHREADS) p[i] = W_proj[i];
        float* q = (float*)s_wk;
        for (int i = threadIdx.x; i < H * H; i += NTHREADS) q[i] = W_k[i];
        if (threadIdx.x < H) {
            ((float*)s_bp)[threadIdx.x] = b_proj[threadIdx.x];
            ((float*)s_bk)[threadIdx.x] = b_k[threadIdx.x];
        }
    }
    __syncthreads();

    const int b = blockIdx.x * NTHREADS + threadIdx.x;  // one row per thread

    const f32x4* crow = (const f32x4*)(item_corpus + (size_t)b * (S * D));

    // ic[s][h] accumulator: 10x16 fp32 in VGPRs, all indices compile-time.
    f32x4 ic[S][4];
    #pragma unroll
    for (int s = 0; s < S; ++s)
        #pragma unroll
        for (int q = 0; q < 4; ++q) ic[s][q] = s_bp[q];

    // Projection: ic[s][:] = sum_d corpus[b][s][d] * Wp[d][:] + bp
    // d processed in quads; per-lane sequential float4 corpus loads.
    for (int i = 0; i < D / 4; ++i) {
        f32x4 w[4][4];
        #pragma unroll
        for (int dd = 0; dd < 4; ++dd)
            #pragma unroll
            for (int q = 0; q < 4; ++q)
                w[dd][q] = s_wp[(4 * i + dd) * 4 + q];
        #pragma unroll
        for (int s = 0; s < S; ++s) {
            f32x4 c = crow[s * (D / 4) + i];
            #pragma unroll
            for (int dd = 0; dd < 4; ++dd) {
                float a = c[dd];
                #pragma unroll
                for (int q = 0; q < 4; ++q)
                    ic[s][q] += a * w[dd][q];
            }
        }
    }

    // ui state: running sum of selected vectors (incl. user_intent).
    const f32x4* urow = (const f32x4*)(user_intent + (size_t)b * H);
    f32x4* orow = (f32x4*)(out + (size_t)b * (6 * H));
    f32x4 usum[4];
    #pragma unroll
    for (int q = 0; q < 4; ++q) {
        f32x4 u = urow[q];
        usum[q] = u;
        orow[q] = u;  // ui[:,0,:] = user_intent
    }

    #pragma unroll
    for (int t = 0; t < NITER; ++t) {
        // ic = ic @ Wk + bk (per-s, in registers; Wk broadcast from LDS)
        #pragma unroll
        for (int s = 0; s < S; ++s) {
            f32x4 nv[4];
            #pragma unroll
            for (int q = 0; q < 4; ++q) nv[q] = s_bk[q];
            #pragma unroll
            for (int k = 0; k < H; ++k) {
                float a = ic[s][k >> 2][k & 3];
                #pragma unroll
                for (int q = 0; q < 4; ++q)
                    nv[q] += a * s_wk[k * 4 + q];
            }
            #pragma unroll
            for (int q = 0; q < 4; ++q) ic[s][q] = nv[q];
        }

        // src = mean(ui) over the t+1 vectors accumulated so far
        float cnt = (float)(t + 1);
        f32x4 src[4];
        #pragma unroll
        for (int q = 0; q < 4; ++q) src[q] = usum[q] / cnt;

        // score[s] = dot(ic[s], src); argmax keeps FIRST max (strict >)
        // (softmax is monotonic -> skip it entirely)
        float best = 0.0f;
        int bidx = 0;
        #pragma unroll
        for (int s = 0; s < S; ++s) {
            float sc = 0.0f;
            #pragma unroll
            for (int q = 0; q < 4; ++q)
                #pragma unroll
                for (int c = 0; c < 4; ++c)
                    sc += ic[s][q][c] * src[q][c];
            if (s == 0 || sc > best) { best = sc; bidx = s; }
        }

        // item_vec = ic[bidx] via unrolled select (no runtime reg indexing)
        f32x4 iv[4];
        #pragma unroll
        for (int q = 0; q < 4; ++q) iv[q] = ic[0][q];
        #pragma unroll
        for (int s = 1; s < S; ++s) {
            bool take = (bidx == s);
            #pragma unroll
            for (int q = 0; q < 4; ++q)
                iv[q] = take ? ic[s][q] : iv[q];
        }

        // append to ui: update running sum, write output row t+1
        #pragma unroll
        for (int q = 0; q < 4; ++q) {
            usum[q] += iv[q];
            orow[(t + 1) * 4 + q] = iv[q];
        }
    }
}

extern "C" void kernel_launch(void* const* d_in, const int* in_sizes, int n_in,
                              void* d_out, int out_size, void* d_ws, size_t ws_size,
                              hipStream_t stream) {
    const float* user_intent = (const float*)d_in[0];
    const float* item_corpus = (const float*)d_in[1];
    const float* W_proj      = (const float*)d_in[2];
    const float* b_proj      = (const float*)d_in[3];
    const float* W_k         = (const float*)d_in[4];
    const float* b_k         = (const float*)d_in[5];
    float* out = (float*)d_out;

    const int bs = 65536;
    hipLaunchKernelGGL(attn_greedy_kernel,
                       dim3(bs / NTHREADS), dim3(NTHREADS), 0, stream,
                       user_intent, item_corpus, W_proj, b_proj, W_k, b_k, out);
}

// Round 2
// 307.804 us; speedup vs baseline: 1.4835x; 1.4835x over previous
//
#include <hip/hip_runtime.h>

typedef __attribute__((ext_vector_type(4))) float f32x4;

#define NT 256
#define S 10
#define D 100
#define H 16
#define NITER 5
#define RQ 25   // LDS out-staging row stride in quads (24 used + 1 pad -> bank spread)
#define OUTQ 24 // quads per output row (6*16 floats)

__global__ __launch_bounds__(NT, 1)
void attn_greedy_kernel(const float* __restrict__ user_intent,
                        const float* __restrict__ item_corpus,
                        const float* __restrict__ W_proj,
                        const float* __restrict__ b_proj,
                        const float* __restrict__ W_k,
                        const float* __restrict__ b_k,
                        float* __restrict__ out)
{
    // Weights: wave-uniform broadcast reads later (conflict-free).
    __shared__ f32x4 s_wp[D * 4];     // wp[d][q], 6400 B
    __shared__ f32x4 s_wk[H * 4];     // wk[k][q], 1024 B
    __shared__ f32x4 s_bp[4];
    __shared__ f32x4 s_bk[4];
    // Output staging: row stride 25 quads so write banks spread ((t+q)%8 groups).
    __shared__ f32x4 s_out[NT * RQ];  // 100 KB

    {
        float* wpf = (float*)s_wp;
        for (int i = threadIdx.x; i < D * H; i += NT) wpf[i] = W_proj[i];
        float* wkf = (float*)s_wk;
        for (int i = threadIdx.x; i < H * H; i += NT) wkf[i] = W_k[i];
        if (threadIdx.x < H) {
            ((float*)s_bp)[threadIdx.x] = b_proj[threadIdx.x];
            ((float*)s_bk)[threadIdx.x] = b_k[threadIdx.x];
        }
    }
    __syncthreads();

    const int t = threadIdx.x;
    const size_t b = (size_t)blockIdx.x * NT + t;   // one row per thread
    const f32x4* crow = (const f32x4*)item_corpus + b * (S * D / 4);

    // user_intent: one full 64B line per lane; stash in s_out row 0..3 now.
    const f32x4* urow = (const f32x4*)user_intent + b * 4;
    f32x4 usum[4];
    #pragma unroll
    for (int q = 0; q < 4; ++q) {
        f32x4 u = urow[q];
        usum[q] = u;
        s_out[t * RQ + q] = u;
    }

    // ---- Projection: s OUTER, i INNER -> each lane streams its row
    // sequentially (1 live cache line per lane -> L1-resident, no re-fetch).
    f32x4 ic[S][4];
    #pragma unroll
    for (int s = 0; s < S; ++s) {
        f32x4 a0 = s_bp[0], a1 = s_bp[1], a2 = s_bp[2], a3 = s_bp[3];
        #pragma unroll 5
        for (int i = 0; i < D / 4; ++i) {
            f32x4 c = crow[s * (D / 4) + i];
            #pragma unroll
            for (int dd = 0; dd < 4; ++dd) {
                float a = c[dd];
                const f32x4* wrow = &s_wp[(i * 4 + dd) * 4];
                a0 += a * wrow[0];
                a1 += a * wrow[1];
                a2 += a * wrow[2];
                a3 += a * wrow[3];
            }
        }
        ic[s][0] = a0; ic[s][1] = a1; ic[s][2] = a2; ic[s][3] = a3;
    }

    // ---- Greedy iterations (runtime loop; no t-indexed register arrays).
    for (int it = 0; it < NITER; ++it) {
        // ic = ic @ Wk + bk, k-outer so each Wk row load amortizes over all s.
        f32x4 nv[S][4];
        #pragma unroll
        for (int s = 0; s < S; ++s)
            #pragma unroll
            for (int q = 0; q < 4; ++q) nv[s][q] = s_bk[q];
        #pragma unroll
        for (int k = 0; k < H; ++k) {
            f32x4 w0 = s_wk[k * 4 + 0], w1 = s_wk[k * 4 + 1];
            f32x4 w2 = s_wk[k * 4 + 2], w3 = s_wk[k * 4 + 3];
            #pragma unroll
            for (int s = 0; s < S; ++s) {
                float a = ic[s][k >> 2][k & 3];
                nv[s][0] += a * w0;
                nv[s][1] += a * w1;
                nv[s][2] += a * w2;
                nv[s][3] += a * w3;
            }
        }
        #pragma unroll
        for (int s = 0; s < S; ++s)
            #pragma unroll
            for (int q = 0; q < 4; ++q) ic[s][q] = nv[s][q];

        // src = mean(ui) over it+1 accumulated vectors
        float cnt = (float)(it + 1);
        f32x4 src[4];
        #pragma unroll
        for (int q = 0; q < 4; ++q) src[q] = usum[q] / cnt;

        // scores + argmax (first max; softmax skipped: monotonic)
        float best = 0.0f;
        int bidx = 0;
        #pragma unroll
        for (int s = 0; s < S; ++s) {
            float sc = 0.0f;
            #pragma unroll
            for (int q = 0; q < 4; ++q)
                #pragma unroll
                for (int c = 0; c < 4; ++c)
                    sc += ic[s][q][c] * src[q][c];
            if (s == 0 || sc > best) { best = sc; bidx = s; }
        }

        // item_vec = ic[bidx] via unrolled select (static register indexing)
        f32x4 iv[4];
        #pragma unroll
        for (int q = 0; q < 4; ++q) iv[q] = ic[0][q];
        #pragma unroll
        for (int s = 1; s < S; ++s) {
            bool take = (bidx == s);
            #pragma unroll
            for (int q = 0; q < 4; ++q)
                iv[q] = take ? ic[s][q] : iv[q];
        }

        #pragma unroll
        for (int q = 0; q < 4; ++q) {
            usum[q] += iv[q];
            s_out[t * RQ + (it + 1) * 4 + q] = iv[q];
        }
    }

    // ---- Coalesced output: block region is contiguous 96 KB; lanes store
    // consecutive 16B -> 1KB/instr, full-line writes only.
    __syncthreads();
    f32x4* out4 = (f32x4*)out;
    const size_t obase = (size_t)blockIdx.x * NT * OUTQ;
    #pragma unroll
    for (int k = 0; k < OUTQ; ++k) {
        int j = t + k * NT;
        int row = j / OUTQ;
        int q = j - row * OUTQ;
        out4[obase + j] = s_out[row * RQ + q];
    }
}

extern "C" void kernel_launch(void* const* d_in, const int* in_sizes, int n_in,
                              void* d_out, int out_size, void* d_ws, size_t ws_size,
                              hipStream_t stream) {
    const float* user_intent = (const float*)d_in[0];
    const float* item_corpus = (const float*)d_in[1];
    const float* W_proj      = (const float*)d_in[2];
    const float* b_proj      = (const float*)d_in[3];
    const float* W_k         = (const float*)d_in[4];
    const float* b_k         = (const float*)d_in[5];
    float* out = (float*)d_out;

    const int bs = 65536;
    hipLaunchKernelGGL(attn_greedy_kernel,
                       dim3(bs / NT), dim3(NT), 0, stream,
                       user_intent, item_corpus, W_proj, b_proj, W_k, b_k, out);
}